// Round 11
// baseline (326.485 us; speedup 1.0000x reference)
//
#include <hip/hip_runtime.h>
#include <math.h>

#define LVL 4
#define NN 65536
#define DD 512
#define NBLK 256                 // partial-sum blocks per level
#define ROWS_PER_BLK (NN / NBLK) // 256
#define LN_EPS 1e-5f
#define ATTN_SCALE 0.08838834764831845f  // (512/4)^-0.5

typedef float f32x4 __attribute__((ext_vector_type(4)));

// ws layout (floats)
#define WS_PARTIALS 0                        // LVL*NBLK*DD = 524288
#define WS_QKV  (WS_PARTIALS + LVL*NBLK*DD)  // 3*LVL*DD (q,k,v)
#define WS_H    (WS_QKV + 3*LVL*DD)          // LVL*DD
#define WS_UPD  (WS_H + LVL*DD)              // LVL*DD

__device__ __forceinline__ void acc4(float4& a, const float4 v) {
    a.x += v.x; a.y += v.y; a.z += v.z; a.w += v.w;
}

// ---------------- K1: partial column sums of x over N (4-acc ILP) ----------------
__global__ __launch_bounds__(256) void colsum_kernel(const float* __restrict__ x,
                                                     float* __restrict__ partials) {
    int blk = blockIdx.x;            // 0 .. LVL*NBLK-1
    int l = blk >> 8;
    int b = blk & 255;
    int t = threadIdx.x;
    int lane = t & 127;              // DD/4 = 128 float4 per row
    int rg = t >> 7;                 // 2 row groups
    const float4* xp = (const float4*)(x + ((size_t)l * NN + (size_t)b * ROWS_PER_BLK) * DD);
    float4 a0 = make_float4(0.f,0.f,0.f,0.f), a1 = a0, a2 = a0, a3 = a0;
    for (int i = 0; i < 128; i += 4) {
        float4 v0 = xp[(size_t)((i + 0) * 2 + rg) * (DD / 4) + lane];
        float4 v1 = xp[(size_t)((i + 1) * 2 + rg) * (DD / 4) + lane];
        float4 v2 = xp[(size_t)((i + 2) * 2 + rg) * (DD / 4) + lane];
        float4 v3 = xp[(size_t)((i + 3) * 2 + rg) * (DD / 4) + lane];
        acc4(a0, v0); acc4(a1, v1); acc4(a2, v2); acc4(a3, v3);
    }
    acc4(a0, a1); acc4(a2, a3); acc4(a0, a2);
    __shared__ float4 red[128];
    if (rg) red[lane] = a0;
    __syncthreads();
    if (!rg) {
        acc4(a0, red[lane]);
        ((float4*)(partials + (size_t)(l * NBLK + b) * DD))[lane] = a0;
    }
}

// ---------------- K2: fused summ-reduce + q/k/v matvec (+W1/W2 L2 prefetch) ------
// grid = 112 blocks: 0..95 main (mat = blk>>5, sub = blk&31: l = sub>>3, ec = sub&7);
// 96..111 stream W1,W2 into L2/L3 so K3/K4 hit warm lines.
__global__ __launch_bounds__(1024) void qkv_kernel(const float* __restrict__ partials,
                                                   const float* __restrict__ Wq,
                                                   const float* __restrict__ bq,
                                                   const float* __restrict__ Wk,
                                                   const float* __restrict__ bk,
                                                   const float* __restrict__ Wv,
                                                   const float* __restrict__ bv,
                                                   const float* __restrict__ W1,
                                                   const float* __restrict__ W2,
                                                   float* __restrict__ qkv) {
    int blk = blockIdx.x;
    int t = threadIdx.x;

    if (blk >= 96) {
        // prefetch W1, W2 (LVL*DD*DD floats each = 262144 float4 each)
        const int NF4 = LVL * DD * DD / 4;
        int idx0 = (blk - 96) * 1024 + t;      // 16 blocks * 1024 threads = 16384
        const float4* w1 = (const float4*)W1;
        const float4* w2 = (const float4*)W2;
        float4 a = make_float4(0.f,0.f,0.f,0.f);
        for (int i = idx0; i < NF4; i += 16384) {
            acc4(a, w1[i]);
            acc4(a, w2[i]);
        }
        float keep = a.x + a.y + a.z + a.w;
        asm volatile("" :: "v"(keep));  // keep loads alive (no DCE)
        return;
    }

    int mat = blk >> 5;
    int sub = blk & 31;
    int l = sub >> 3, ec = sub & 7;
    const float* W    = (mat == 0) ? Wq : (mat == 1) ? Wk : Wv;
    const float* bias = (mat == 0) ? bq : (mat == 1) ? bk : bv;

    __shared__ float summ[DD];
    __shared__ float red[1024];

    // reduce partials[l][0..255][d] -> summ[d]
    {
        int d = t & 511, half = t >> 9;
        const float* p = partials + (size_t)l * NBLK * DD + d;
        float s0 = 0.f, s1 = 0.f;
        for (int b = half * 128; b < half * 128 + 128; b += 2) {
            s0 += p[(size_t)b * DD];
            s1 += p[(size_t)(b + 1) * DD];
        }
        float s = s0 + s1;
        if (half) red[d] = s;
        __syncthreads();
        if (!half) summ[d] = (s + red[d]) * (1.0f / NN);
        __syncthreads();
    }

    // matvec: 64 e-cols x 16 d-groups of 32
    int e = t & 63, dg = t >> 6;
    int ecol = ec * 64 + e;
    const float* Wl = W + (size_t)l * DD * DD;
    float acc = 0.f;
    for (int d = dg * 32; d < dg * 32 + 32; ++d)
        acc += summ[d] * Wl[(size_t)d * DD + ecol];
    red[t] = acc;
    __syncthreads();
    for (int s = 512; s >= 64; s >>= 1) {
        if (t < s) red[t] += red[t + s];
        __syncthreads();
    }
    if (t < 64)
        qkv[(size_t)mat * LVL * DD + (size_t)l * DD + ec * 64 + t] =
            red[t] + bias[(size_t)l * DD + ec * 64 + t];
}

// ---------------- K3: fused attention softmax + ctx + W1 matvec slice (ReLU) -------
// R5 structure: 32 blocks, each computes a 64-col h slice (W1 reads non-redundant).
__global__ __launch_bounds__(1024) void attn_h_kernel(const float* __restrict__ qkv,
                                                      const float* __restrict__ W1,
                                                      const float* __restrict__ b1,
                                                      float* __restrict__ h) {
    int l = blockIdx.x >> 3, ec = blockIdx.x & 7;
    int t = threadIdx.x;
    const float* q = qkv;
    const float* k = qkv + LVL * DD;
    const float* v = qkv + 2 * LVL * DD;

    __shared__ float red[1024];
    __shared__ float atw[LVL];
    __shared__ float ctx[DD];

    // scores: 4 dots of 512
    {
        int j = t >> 8, dd = t & 255;
        float a = q[l * DD + dd] * k[j * DD + dd]
                + q[l * DD + dd + 256] * k[j * DD + dd + 256];
        red[t] = a;
        __syncthreads();
        for (int s = 128; s >= 1; s >>= 1) {
            if ((t & 255) < s) red[t] += red[t + s];
            __syncthreads();
        }
        if (t == 0) {
            float sc[LVL], m = -1e30f;
            for (int jj = 0; jj < LVL; ++jj) {
                sc[jj] = (jj == l) ? -1e30f : red[jj * 256] * ATTN_SCALE;
                m = fmaxf(m, sc[jj]);
            }
            float ssum = 0.f;
            for (int jj = 0; jj < LVL; ++jj) { sc[jj] = expf(sc[jj] - m); ssum += sc[jj]; }
            float inv = 1.0f / ssum;
            for (int jj = 0; jj < LVL; ++jj) atw[jj] = sc[jj] * inv;
        }
        __syncthreads();
    }

    if (t < DD) {
        float c = 0.f;
        for (int jj = 0; jj < LVL; ++jj) c += atw[jj] * v[jj * DD + t];
        ctx[t] = c;
    }
    __syncthreads();

    int e = t & 63, dg = t >> 6;
    int ecol = ec * 64 + e;
    const float* Wl = W1 + (size_t)l * DD * DD;
    float acc = 0.f;
    for (int d = dg * 32; d < dg * 32 + 32; ++d)
        acc += ctx[d] * Wl[(size_t)d * DD + ecol];
    red[t] = acc;
    __syncthreads();
    for (int s = 512; s >= 64; s >>= 1) {
        if (t < s) red[t] += red[t + s];
        __syncthreads();
    }
    if (t < 64) {
        float r = red[t] + b1[(size_t)l * DD + ec * 64 + t];
        h[(size_t)l * DD + ec * 64 + t] = fmaxf(r, 0.f);
    }
}

// ---------------- K4: upd matvec ----------------
__global__ __launch_bounds__(1024) void matvec1024_kernel(const float* __restrict__ in,
                                                          const float* __restrict__ W,
                                                          const float* __restrict__ bias,
                                                          float* __restrict__ out) {
    int l = blockIdx.x >> 3, ec = blockIdx.x & 7;
    int t = threadIdx.x;
    __shared__ float red[1024];
    int e = t & 63, dg = t >> 6;
    int ecol = ec * 64 + e;
    const float* iv = in + (size_t)l * DD;
    const float* Wl = W + (size_t)l * DD * DD;
    float acc = 0.f;
    for (int d = dg * 32; d < dg * 32 + 32; ++d)
        acc += iv[d] * Wl[(size_t)d * DD + ecol];
    red[t] = acc;
    __syncthreads();
    for (int s = 512; s >= 64; s >>= 1) {
        if (t < s) red[t] += red[t + s];
        __syncthreads();
    }
    if (t < 64)
        out[(size_t)l * DD + ec * 64 + t] = red[t] + bias[(size_t)l * DD + ec * 64 + t];
}

// ---------------- K5: fused residual add + LayerNorm (4-row unroll) ----------------
// Descending; NT stores (A/B-proven R8/R9: protect x L3 residency, -39 us).
// 4 consecutive rows per wave-iteration: 8-load burst, 8 interleaved shuffle
// chains, 8-store burst -> better HBM direction locality + latency cover.
// Groups of 4 are 4-aligned so they never straddle a level (65536-row) boundary.
__global__ __launch_bounds__(256) void final_ln_kernel(const float* __restrict__ x,
                                                       const float* __restrict__ upd,
                                                       const float* __restrict__ gamma,
                                                       const float* __restrict__ beta,
                                                       float* __restrict__ out) {
    int lane = threadIdx.x & 63;
    int wid = (blockIdx.x * blockDim.x + threadIdx.x) >> 6;
    const int NW = (2048 * 256) >> 6;          // 8192 waves
    const int totalRows = LVL * NN;            // 262144
    int lprev = -1;
    float4 u0, u1, g0, g1, p0, p1;
    for (int it = wid * 4; it < totalRows; it += NW * 4) {
        int r0 = totalRows - 4 - it;           // 4-aligned; rows r0..r0+3 same level
        int l = r0 >> 16;                      // NN = 65536
        if (l != lprev) {
            lprev = l;
            const float4* ur = (const float4*)(upd + (size_t)l * DD);
            u0 = ur[lane]; u1 = ur[64 + lane];
            const float4* gr = (const float4*)(gamma + (size_t)l * DD);
            g0 = gr[lane]; g1 = gr[64 + lane];
            const float4* br = (const float4*)(beta + (size_t)l * DD);
            p0 = br[lane]; p1 = br[64 + lane];
        }
        const float4* xr = (const float4*)(x + (size_t)r0 * DD);  // row stride = 128 float4
        // 8-load burst (independent)
        float4 a0 = xr[lane],        c0 = xr[64 + lane];
        float4 a1 = xr[128 + lane],  c1 = xr[192 + lane];
        float4 a2 = xr[256 + lane],  c2 = xr[320 + lane];
        float4 a3 = xr[384 + lane],  c3 = xr[448 + lane];
        acc4(a0, u0); acc4(c0, u1);
        acc4(a1, u0); acc4(c1, u1);
        acc4(a2, u0); acc4(c2, u1);
        acc4(a3, u0); acc4(c3, u1);
        float s0  = a0.x + a0.y + a0.z + a0.w + c0.x + c0.y + c0.z + c0.w;
        float sq0 = a0.x*a0.x + a0.y*a0.y + a0.z*a0.z + a0.w*a0.w
                  + c0.x*c0.x + c0.y*c0.y + c0.z*c0.z + c0.w*c0.w;
        float s1  = a1.x + a1.y + a1.z + a1.w + c1.x + c1.y + c1.z + c1.w;
        float sq1 = a1.x*a1.x + a1.y*a1.y + a1.z*a1.z + a1.w*a1.w
                  + c1.x*c1.x + c1.y*c1.y + c1.z*c1.z + c1.w*c1.w;
        float s2  = a2.x + a2.y + a2.z + a2.w + c2.x + c2.y + c2.z + c2.w;
        float sq2 = a2.x*a2.x + a2.y*a2.y + a2.z*a2.z + a2.w*a2.w
                  + c2.x*c2.x + c2.y*c2.y + c2.z*c2.z + c2.w*c2.w;
        float s3  = a3.x + a3.y + a3.z + a3.w + c3.x + c3.y + c3.z + c3.w;
        float sq3 = a3.x*a3.x + a3.y*a3.y + a3.z*a3.z + a3.w*a3.w
                  + c3.x*c3.x + c3.y*c3.y + c3.z*c3.z + c3.w*c3.w;
        for (int off = 32; off >= 1; off >>= 1) {
            s0  += __shfl_down(s0, off);   sq0 += __shfl_down(sq0, off);
            s1  += __shfl_down(s1, off);   sq1 += __shfl_down(sq1, off);
            s2  += __shfl_down(s2, off);   sq2 += __shfl_down(sq2, off);
            s3  += __shfl_down(s3, off);   sq3 += __shfl_down(sq3, off);
        }
        s0 = __shfl(s0, 0);  sq0 = __shfl(sq0, 0);
        s1 = __shfl(s1, 0);  sq1 = __shfl(sq1, 0);
        s2 = __shfl(s2, 0);  sq2 = __shfl(sq2, 0);
        s3 = __shfl(s3, 0);  sq3 = __shfl(sq3, 0);
        float mu0 = s0 * (1.0f / DD), var0 = sq0 * (1.0f / DD) - mu0 * mu0;
        float mu1 = s1 * (1.0f / DD), var1 = sq1 * (1.0f / DD) - mu1 * mu1;
        float mu2 = s2 * (1.0f / DD), var2 = sq2 * (1.0f / DD) - mu2 * mu2;
        float mu3 = s3 * (1.0f / DD), var3 = sq3 * (1.0f / DD) - mu3 * mu3;
        float inv0 = rsqrtf(var0 + LN_EPS);
        float inv1 = rsqrtf(var1 + LN_EPS);
        float inv2 = rsqrtf(var2 + LN_EPS);
        float inv3 = rsqrtf(var3 + LN_EPS);
        f32x4* orow = (f32x4*)(out + (size_t)r0 * DD);
        float4 o;
#define LN_OUT(av, g, p, inv, mu, idx)                                   \
        o.x = ((av).x - (mu)) * (inv) * (g).x + (p).x;                   \
        o.y = ((av).y - (mu)) * (inv) * (g).y + (p).y;                   \
        o.z = ((av).z - (mu)) * (inv) * (g).z + (p).z;                   \
        o.w = ((av).w - (mu)) * (inv) * (g).w + (p).w;                   \
        __builtin_nontemporal_store(*(const f32x4*)&o, orow + (idx));
        LN_OUT(a0, g0, p0, inv0, mu0, lane)
        LN_OUT(c0, g1, p1, inv0, mu0, 64 + lane)
        LN_OUT(a1, g0, p0, inv1, mu1, 128 + lane)
        LN_OUT(c1, g1, p1, inv1, mu1, 192 + lane)
        LN_OUT(a2, g0, p0, inv2, mu2, 256 + lane)
        LN_OUT(c2, g1, p1, inv2, mu2, 320 + lane)
        LN_OUT(a3, g0, p0, inv3, mu3, 384 + lane)
        LN_OUT(c3, g1, p1, inv3, mu3, 448 + lane)
#undef LN_OUT
    }
}

extern "C" void kernel_launch(void* const* d_in, const int* in_sizes, int n_in,
                              void* d_out, int out_size, void* d_ws, size_t ws_size,
                              hipStream_t stream) {
    const float* x     = (const float*)d_in[0];
    const float* Wq    = (const float*)d_in[1];
    const float* bq    = (const float*)d_in[2];
    const float* Wk    = (const float*)d_in[3];
    const float* bk    = (const float*)d_in[4];
    const float* Wv    = (const float*)d_in[5];
    const float* bv    = (const float*)d_in[6];
    const float* W1    = (const float*)d_in[7];
    const float* b1    = (const float*)d_in[8];
    const float* W2    = (const float*)d_in[9];
    const float* b2    = (const float*)d_in[10];
    const float* gamma = (const float*)d_in[11];
    const float* beta  = (const float*)d_in[12];
    float* out = (float*)d_out;
    float* ws = (float*)d_ws;

    float* partials = ws + WS_PARTIALS;
    float* qkv      = ws + WS_QKV;
    float* h        = ws + WS_H;
    float* upd      = ws + WS_UPD;

    colsum_kernel<<<LVL * NBLK, 256, 0, stream>>>(x, partials);
    qkv_kernel<<<112, 1024, 0, stream>>>(partials, Wq, bq, Wk, bk, Wv, bv, W1, W2, qkv);
    attn_h_kernel<<<32, 1024, 0, stream>>>(qkv, W1, b1, h);
    matvec1024_kernel<<<32, 1024, 0, stream>>>(h, W2, b2, upd);
    final_ln_kernel<<<2048, 256, 0, stream>>>(x, upd, gamma, beta, out);
}

// Round 12
// 313.957 us; speedup vs baseline: 1.0399x; 1.0399x over previous
//
#include <hip/hip_runtime.h>
#include <math.h>

#define LVL 4
#define NN 65536
#define DD 512
#define NBLK 256                 // partial-sum blocks per level
#define ROWS_PER_BLK (NN / NBLK) // 256
#define PFB 32                   // trailing prefetch blocks (Wq/Wk/Wv)
#define LN_EPS 1e-5f
#define ATTN_SCALE 0.08838834764831845f  // (512/4)^-0.5

typedef float f32x4 __attribute__((ext_vector_type(4)));

// ws layout (floats)
#define WS_PARTIALS 0                        // LVL*NBLK*DD = 524288
#define WS_QKV  (WS_PARTIALS + LVL*NBLK*DD)  // 3*LVL*DD (q,k,v)
#define WS_UPD  (WS_QKV + 3*LVL*DD)          // LVL*DD

__device__ __forceinline__ void acc4(float4& a, const float4 v) {
    a.x += v.x; a.y += v.y; a.z += v.z; a.w += v.w;
}

// ---------------- K1: partial column sums of x over N (4-acc ILP) --------------
// Blocks >= LVL*NBLK are TRAILING prefetch blocks: they dispatch after all
// colsum blocks (fill the CU-drain tail) and stream Wq/Wk/Wv (12 MB) into
// L2/L3 so qkv_kernel reads warm weights. (R7 showed FRONT placement delays
// colsum and loses 16 us; trailing placement overlaps the tail instead.)
__global__ __launch_bounds__(256) void colsum_kernel(const float* __restrict__ x,
                                                     const float* __restrict__ Wq,
                                                     const float* __restrict__ Wk,
                                                     const float* __restrict__ Wv,
                                                     float* __restrict__ partials) {
    int blk = blockIdx.x;
    int t = threadIdx.x;

    if (blk >= LVL * NBLK) {
        const int NF4 = LVL * DD * DD / 4;     // 262144 float4 per matrix
        int idx0 = (blk - LVL * NBLK) * 256 + t;   // PFB*256 = 8192 threads
        const float4* wq = (const float4*)Wq;
        const float4* wk = (const float4*)Wk;
        const float4* wv = (const float4*)Wv;
        float4 a = make_float4(0.f,0.f,0.f,0.f);
        for (int i = idx0; i < NF4; i += PFB * 256) {
            acc4(a, wq[i]);
            acc4(a, wk[i]);
            acc4(a, wv[i]);
        }
        float keep = a.x + a.y + a.z + a.w;
        asm volatile("" :: "v"(keep));  // keep loads alive (no DCE)
        return;
    }

    int l = blk >> 8;
    int b = blk & 255;
    int lane = t & 127;              // DD/4 = 128 float4 per row
    int rg = t >> 7;                 // 2 row groups
    const float4* xp = (const float4*)(x + ((size_t)l * NN + (size_t)b * ROWS_PER_BLK) * DD);
    float4 a0 = make_float4(0.f,0.f,0.f,0.f), a1 = a0, a2 = a0, a3 = a0;
    for (int i = 0; i < 128; i += 4) {
        float4 v0 = xp[(size_t)((i + 0) * 2 + rg) * (DD / 4) + lane];
        float4 v1 = xp[(size_t)((i + 1) * 2 + rg) * (DD / 4) + lane];
        float4 v2 = xp[(size_t)((i + 2) * 2 + rg) * (DD / 4) + lane];
        float4 v3 = xp[(size_t)((i + 3) * 2 + rg) * (DD / 4) + lane];
        acc4(a0, v0); acc4(a1, v1); acc4(a2, v2); acc4(a3, v3);
    }
    acc4(a0, a1); acc4(a2, a3); acc4(a0, a2);
    __shared__ float4 red[128];
    if (rg) red[lane] = a0;
    __syncthreads();
    if (!rg) {
        acc4(a0, red[lane]);
        ((float4*)(partials + (size_t)(l * NBLK + b) * DD))[lane] = a0;
    }
}

// ---------------- K2: fused summ-reduce + q/k/v matvec (+W1/W2 L2 prefetch) ------
// grid = 112 blocks: 0..95 main (mat = blk>>5, sub = blk&31: l = sub>>3, ec = sub&7);
// 96..111 stream W1,W2 into L2/L3 so K3 hits warm lines.
__global__ __launch_bounds__(1024) void qkv_kernel(const float* __restrict__ partials,
                                                   const float* __restrict__ Wq,
                                                   const float* __restrict__ bq,
                                                   const float* __restrict__ Wk,
                                                   const float* __restrict__ bk,
                                                   const float* __restrict__ Wv,
                                                   const float* __restrict__ bv,
                                                   const float* __restrict__ W1,
                                                   const float* __restrict__ W2,
                                                   float* __restrict__ qkv) {
    int blk = blockIdx.x;
    int t = threadIdx.x;

    if (blk >= 96) {
        // prefetch W1, W2 (LVL*DD*DD floats each = 262144 float4 each)
        const int NF4 = LVL * DD * DD / 4;
        int idx0 = (blk - 96) * 1024 + t;      // 16 blocks * 1024 threads = 16384
        const float4* w1 = (const float4*)W1;
        const float4* w2 = (const float4*)W2;
        float4 a = make_float4(0.f,0.f,0.f,0.f);
        for (int i = idx0; i < NF4; i += 16384) {
            acc4(a, w1[i]);
            acc4(a, w2[i]);
        }
        float keep = a.x + a.y + a.z + a.w;
        asm volatile("" :: "v"(keep));  // keep loads alive (no DCE)
        return;
    }

    int mat = blk >> 5;
    int sub = blk & 31;
    int l = sub >> 3, ec = sub & 7;
    const float* W    = (mat == 0) ? Wq : (mat == 1) ? Wk : Wv;
    const float* bias = (mat == 0) ? bq : (mat == 1) ? bk : bv;

    __shared__ float summ[DD];
    __shared__ float red[1024];

    // reduce partials[l][0..255][d] -> summ[d]
    {
        int d = t & 511, half = t >> 9;
        const float* p = partials + (size_t)l * NBLK * DD + d;
        float s0 = 0.f, s1 = 0.f;
        for (int b = half * 128; b < half * 128 + 128; b += 2) {
            s0 += p[(size_t)b * DD];
            s1 += p[(size_t)(b + 1) * DD];
        }
        float s = s0 + s1;
        if (half) red[d] = s;
        __syncthreads();
        if (!half) summ[d] = (s + red[d]) * (1.0f / NN);
        __syncthreads();
    }

    // matvec: 64 e-cols x 16 d-groups of 32
    int e = t & 63, dg = t >> 6;
    int ecol = ec * 64 + e;
    const float* Wl = W + (size_t)l * DD * DD;
    float acc = 0.f;
    for (int d = dg * 32; d < dg * 32 + 32; ++d)
        acc += summ[d] * Wl[(size_t)d * DD + ecol];
    red[t] = acc;
    __syncthreads();
    for (int s = 512; s >= 64; s >>= 1) {
        if (t < s) red[t] += red[t + s];
        __syncthreads();
    }
    if (t < 64)
        qkv[(size_t)mat * LVL * DD + (size_t)l * DD + ec * 64 + t] =
            red[t] + bias[(size_t)l * DD + ec * 64 + t];
}

// ---------------- K3: fused attn softmax + ctx + FULL h + upd slice ----------------
// grid = 32 blocks (l = blk>>3, ec = blk&7), 1024 threads.  (R10 structure)
__global__ __launch_bounds__(1024) void attn_mlp_kernel(const float* __restrict__ qkv,
                                                        const float* __restrict__ W1,
                                                        const float* __restrict__ b1,
                                                        const float* __restrict__ W2,
                                                        const float* __restrict__ b2,
                                                        float* __restrict__ upd) {
    int l = blockIdx.x >> 3, ec = blockIdx.x & 7;
    int t = threadIdx.x;
    const float* q = qkv;
    const float* k = qkv + LVL * DD;
    const float* v = qkv + 2 * LVL * DD;

    __shared__ float red[1024];
    __shared__ float atw[LVL];
    __shared__ float ctx[DD];
    __shared__ float hsh[DD];

    // scores: 4 dots of 512
    {
        int j = t >> 8, dd = t & 255;
        float a = q[l * DD + dd] * k[j * DD + dd]
                + q[l * DD + dd + 256] * k[j * DD + dd + 256];
        red[t] = a;
        __syncthreads();
        for (int s = 128; s >= 1; s >>= 1) {
            if ((t & 255) < s) red[t] += red[t + s];
            __syncthreads();
        }
        if (t == 0) {
            float sc[LVL], m = -1e30f;
            for (int jj = 0; jj < LVL; ++jj) {
                sc[jj] = (jj == l) ? -1e30f : red[jj * 256] * ATTN_SCALE;
                m = fmaxf(m, sc[jj]);
            }
            float ssum = 0.f;
            for (int jj = 0; jj < LVL; ++jj) { sc[jj] = expf(sc[jj] - m); ssum += sc[jj]; }
            float inv = 1.0f / ssum;
            for (int jj = 0; jj < LVL; ++jj) atw[jj] = sc[jj] * inv;
        }
        __syncthreads();
    }

    // ctx[d] = sum_j atw[j] * v[j][d]
    if (t < DD) {
        float c = 0.f;
        for (int jj = 0; jj < LVL; ++jj) c += atw[jj] * v[jj * DD + t];
        ctx[t] = c;
    }
    __syncthreads();

    // FULL h in LDS: 512 cols x 2 d-halves (coalesced W1 row reads), LDS combine
    {
        int e = t & 511, dh = t >> 9;   // dh = 0/1
        const float* W1l = W1 + (size_t)l * DD * DD;
        int dbase = dh * 256;
        float a0 = 0.f, a1 = 0.f, a2 = 0.f, a3 = 0.f;
        for (int d = 0; d < 256; d += 4) {
            a0 += ctx[dbase + d]     * W1l[(size_t)(dbase + d)     * DD + e];
            a1 += ctx[dbase + d + 1] * W1l[(size_t)(dbase + d + 1) * DD + e];
            a2 += ctx[dbase + d + 2] * W1l[(size_t)(dbase + d + 2) * DD + e];
            a3 += ctx[dbase + d + 3] * W1l[(size_t)(dbase + d + 3) * DD + e];
        }
        red[t] = (a0 + a1) + (a2 + a3);
        __syncthreads();
        if (t < 512)
            hsh[t] = fmaxf(red[t] + red[t + 512] + b1[(size_t)l * DD + t], 0.f);
        __syncthreads();
    }

    // upd slice: 64 e-cols x 16 d-groups of 32, h from LDS
    {
        int e = t & 63, dg = t >> 6;
        int ecol = ec * 64 + e;
        const float* W2l = W2 + (size_t)l * DD * DD;
        float acc = 0.f;
        for (int d = dg * 32; d < dg * 32 + 32; ++d)
            acc += hsh[d] * W2l[(size_t)d * DD + ecol];
        red[t] = acc;
        __syncthreads();
        for (int s = 512; s >= 64; s >>= 1) {
            if (t < s) red[t] += red[t + s];
            __syncthreads();
        }
        if (t < 64)
            upd[(size_t)l * DD + ec * 64 + t] =
                red[t] + b2[(size_t)l * DD + ec * 64 + t];
    }
}

// ---------------- K4: fused residual add + LayerNorm (2-row unroll, R10) ----------
// Descending; NT stores (A/B-proven R8/R9: protect x L3 residency, -39 us).
// 2-row unroll stays under the 64-VGPR occupancy cliff (R11's 4-row crossed it).
__global__ __launch_bounds__(256) void final_ln_kernel(const float* __restrict__ x,
                                                       const float* __restrict__ upd,
                                                       const float* __restrict__ gamma,
                                                       const float* __restrict__ beta,
                                                       float* __restrict__ out) {
    int lane = threadIdx.x & 63;
    int wid = (blockIdx.x * blockDim.x + threadIdx.x) >> 6;
    const int NW = (2048 * 256) >> 6;          // 8192 waves
    const int totalRows = LVL * NN;            // 262144
    int lprev = -1;
    float4 u0, u1, g0, g1, p0, p1;
    for (int it = wid * 2; it < totalRows; it += NW * 2) {
        int r0 = totalRows - 2 - it;           // even; pair (r0, r0+1) same level
        int l = r0 >> 16;                      // NN = 65536
        if (l != lprev) {
            lprev = l;
            const float4* ur = (const float4*)(upd + (size_t)l * DD);
            u0 = ur[lane]; u1 = ur[64 + lane];
            const float4* gr = (const float4*)(gamma + (size_t)l * DD);
            g0 = gr[lane]; g1 = gr[64 + lane];
            const float4* br = (const float4*)(beta + (size_t)l * DD);
            p0 = br[lane]; p1 = br[64 + lane];
        }
        const float4* xr0 = (const float4*)(x + (size_t)r0 * DD);
        const float4* xr1 = (const float4*)(x + (size_t)(r0 + 1) * DD);
        float4 a0 = xr0[lane];
        float4 c0 = xr0[64 + lane];
        float4 a1 = xr1[lane];
        float4 c1 = xr1[64 + lane];
        acc4(a0, u0); acc4(c0, u1);
        acc4(a1, u0); acc4(c1, u1);
        float s0  = a0.x + a0.y + a0.z + a0.w + c0.x + c0.y + c0.z + c0.w;
        float sq0 = a0.x*a0.x + a0.y*a0.y + a0.z*a0.z + a0.w*a0.w
                  + c0.x*c0.x + c0.y*c0.y + c0.z*c0.z + c0.w*c0.w;
        float s1  = a1.x + a1.y + a1.z + a1.w + c1.x + c1.y + c1.z + c1.w;
        float sq1 = a1.x*a1.x + a1.y*a1.y + a1.z*a1.z + a1.w*a1.w
                  + c1.x*c1.x + c1.y*c1.y + c1.z*c1.z + c1.w*c1.w;
        for (int off = 32; off >= 1; off >>= 1) {
            s0  += __shfl_down(s0, off);
            sq0 += __shfl_down(sq0, off);
            s1  += __shfl_down(s1, off);
            sq1 += __shfl_down(sq1, off);
        }
        s0 = __shfl(s0, 0);  sq0 = __shfl(sq0, 0);
        s1 = __shfl(s1, 0);  sq1 = __shfl(sq1, 0);
        float mu0 = s0 * (1.0f / DD);
        float var0 = sq0 * (1.0f / DD) - mu0 * mu0;
        float inv0 = rsqrtf(var0 + LN_EPS);
        float mu1 = s1 * (1.0f / DD);
        float var1 = sq1 * (1.0f / DD) - mu1 * mu1;
        float inv1 = rsqrtf(var1 + LN_EPS);
        float4 o;
        float* orow0 = out + (size_t)r0 * DD;
        float* orow1 = out + (size_t)(r0 + 1) * DD;
        o.x = (a0.x - mu0) * inv0 * g0.x + p0.x;
        o.y = (a0.y - mu0) * inv0 * g0.y + p0.y;
        o.z = (a0.z - mu0) * inv0 * g0.z + p0.z;
        o.w = (a0.w - mu0) * inv0 * g0.w + p0.w;
        __builtin_nontemporal_store(*(const f32x4*)&o, (f32x4*)(orow0) + lane);
        o.x = (c0.x - mu0) * inv0 * g1.x + p1.x;
        o.y = (c0.y - mu0) * inv0 * g1.y + p1.y;
        o.z = (c0.z - mu0) * inv0 * g1.z + p1.z;
        o.w = (c0.w - mu0) * inv0 * g1.w + p1.w;
        __builtin_nontemporal_store(*(const f32x4*)&o, (f32x4*)(orow0) + 64 + lane);
        o.x = (a1.x - mu1) * inv1 * g0.x + p0.x;
        o.y = (a1.y - mu1) * inv1 * g0.y + p0.y;
        o.z = (a1.z - mu1) * inv1 * g0.z + p0.z;
        o.w = (a1.w - mu1) * inv1 * g0.w + p0.w;
        __builtin_nontemporal_store(*(const f32x4*)&o, (f32x4*)(orow1) + lane);
        o.x = (c1.x - mu1) * inv1 * g1.x + p1.x;
        o.y = (c1.y - mu1) * inv1 * g1.y + p1.y;
        o.z = (c1.z - mu1) * inv1 * g1.z + p1.z;
        o.w = (c1.w - mu1) * inv1 * g1.w + p1.w;
        __builtin_nontemporal_store(*(const f32x4*)&o, (f32x4*)(orow1) + 64 + lane);
    }
}

extern "C" void kernel_launch(void* const* d_in, const int* in_sizes, int n_in,
                              void* d_out, int out_size, void* d_ws, size_t ws_size,
                              hipStream_t stream) {
    const float* x     = (const float*)d_in[0];
    const float* Wq    = (const float*)d_in[1];
    const float* bq    = (const float*)d_in[2];
    const float* Wk    = (const float*)d_in[3];
    const float* bk    = (const float*)d_in[4];
    const float* Wv    = (const float*)d_in[5];
    const float* bv    = (const float*)d_in[6];
    const float* W1    = (const float*)d_in[7];
    const float* b1    = (const float*)d_in[8];
    const float* W2    = (const float*)d_in[9];
    const float* b2    = (const float*)d_in[10];
    const float* gamma = (const float*)d_in[11];
    const float* beta  = (const float*)d_in[12];
    float* out = (float*)d_out;
    float* ws = (float*)d_ws;

    float* partials = ws + WS_PARTIALS;
    float* qkv      = ws + WS_QKV;
    float* upd      = ws + WS_UPD;

    colsum_kernel<<<LVL * NBLK + PFB, 256, 0, stream>>>(x, Wq, Wk, Wv, partials);
    qkv_kernel<<<112, 1024, 0, stream>>>(partials, Wq, bq, Wk, bk, Wv, bv, W1, W2, qkv);
    attn_mlp_kernel<<<32, 1024, 0, stream>>>(qkv, W1, b1, W2, b2, upd);
    final_ln_kernel<<<2048, 256, 0, stream>>>(x, upd, gamma, beta, out);
}

// Round 13
// 296.399 us; speedup vs baseline: 1.1015x; 1.0592x over previous
//
#include <hip/hip_runtime.h>
#include <math.h>

#define LVL 4
#define NN 65536
#define DD 512
#define NBLK 256                 // partial-sum blocks per level
#define ROWS_PER_BLK (NN / NBLK) // 256
#define LN_EPS 1e-5f
#define ATTN_SCALE 0.08838834764831845f  // (512/4)^-0.5

typedef float f32x4 __attribute__((ext_vector_type(4)));

// ws layout (floats)
#define WS_PARTIALS 0                        // LVL*NBLK*DD = 524288
#define WS_QKV  (WS_PARTIALS + LVL*NBLK*DD)  // 3*LVL*DD (q,k,v)
#define WS_H    (WS_QKV + 3*LVL*DD)          // LVL*DD
#define WS_UPD  (WS_H + LVL*DD)              // LVL*DD

__device__ __forceinline__ void acc4(float4& a, const float4 v) {
    a.x += v.x; a.y += v.y; a.z += v.z; a.w += v.w;
}

// ---------------- K1: partial column sums of x over N (4-acc ILP) ----------------
__global__ __launch_bounds__(256) void colsum_kernel(const float* __restrict__ x,
                                                     float* __restrict__ partials) {
    int blk = blockIdx.x;            // 0 .. LVL*NBLK-1
    int l = blk >> 8;
    int b = blk & 255;
    int t = threadIdx.x;
    int lane = t & 127;              // DD/4 = 128 float4 per row
    int rg = t >> 7;                 // 2 row groups
    const float4* xp = (const float4*)(x + ((size_t)l * NN + (size_t)b * ROWS_PER_BLK) * DD);
    float4 a0 = make_float4(0.f,0.f,0.f,0.f), a1 = a0, a2 = a0, a3 = a0;
    for (int i = 0; i < 128; i += 4) {
        float4 v0 = xp[(size_t)((i + 0) * 2 + rg) * (DD / 4) + lane];
        float4 v1 = xp[(size_t)((i + 1) * 2 + rg) * (DD / 4) + lane];
        float4 v2 = xp[(size_t)((i + 2) * 2 + rg) * (DD / 4) + lane];
        float4 v3 = xp[(size_t)((i + 3) * 2 + rg) * (DD / 4) + lane];
        acc4(a0, v0); acc4(a1, v1); acc4(a2, v2); acc4(a3, v3);
    }
    acc4(a0, a1); acc4(a2, a3); acc4(a0, a2);
    __shared__ float4 red[128];
    if (rg) red[lane] = a0;
    __syncthreads();
    if (!rg) {
        acc4(a0, red[lane]);
        ((float4*)(partials + (size_t)(l * NBLK + b) * DD))[lane] = a0;
    }
}

// ---------------- K2: fused summ-reduce + q/k/v matvec (+W1/W2 L2 prefetch) ------
// grid = 112 blocks: 0..95 main (mat = blk>>5, sub = blk&31: l = sub>>3, ec = sub&7);
// 96..111 stream W1,W2 into L2/L3 so K3/K4 hit warm lines.
__global__ __launch_bounds__(1024) void qkv_kernel(const float* __restrict__ partials,
                                                   const float* __restrict__ Wq,
                                                   const float* __restrict__ bq,
                                                   const float* __restrict__ Wk,
                                                   const float* __restrict__ bk,
                                                   const float* __restrict__ Wv,
                                                   const float* __restrict__ bv,
                                                   const float* __restrict__ W1,
                                                   const float* __restrict__ W2,
                                                   float* __restrict__ qkv) {
    int blk = blockIdx.x;
    int t = threadIdx.x;

    if (blk >= 96) {
        // prefetch W1, W2 (LVL*DD*DD floats each = 262144 float4 each)
        const int NF4 = LVL * DD * DD / 4;
        int idx0 = (blk - 96) * 1024 + t;      // 16 blocks * 1024 threads = 16384
        const float4* w1 = (const float4*)W1;
        const float4* w2 = (const float4*)W2;
        float4 a = make_float4(0.f,0.f,0.f,0.f);
        for (int i = idx0; i < NF4; i += 16384) {
            acc4(a, w1[i]);
            acc4(a, w2[i]);
        }
        float keep = a.x + a.y + a.z + a.w;
        asm volatile("" :: "v"(keep));  // keep loads alive (no DCE)
        return;
    }

    int mat = blk >> 5;
    int sub = blk & 31;
    int l = sub >> 3, ec = sub & 7;
    const float* W    = (mat == 0) ? Wq : (mat == 1) ? Wk : Wv;
    const float* bias = (mat == 0) ? bq : (mat == 1) ? bk : bv;

    __shared__ float summ[DD];
    __shared__ float red[1024];

    // reduce partials[l][0..255][d] -> summ[d]
    {
        int d = t & 511, half = t >> 9;
        const float* p = partials + (size_t)l * NBLK * DD + d;
        float s0 = 0.f, s1 = 0.f;
        for (int b = half * 128; b < half * 128 + 128; b += 2) {
            s0 += p[(size_t)b * DD];
            s1 += p[(size_t)(b + 1) * DD];
        }
        float s = s0 + s1;
        if (half) red[d] = s;
        __syncthreads();
        if (!half) summ[d] = (s + red[d]) * (1.0f / NN);
        __syncthreads();
    }

    // matvec: 64 e-cols x 16 d-groups of 32
    int e = t & 63, dg = t >> 6;
    int ecol = ec * 64 + e;
    const float* Wl = W + (size_t)l * DD * DD;
    float acc = 0.f;
    for (int d = dg * 32; d < dg * 32 + 32; ++d)
        acc += summ[d] * Wl[(size_t)d * DD + ecol];
    red[t] = acc;
    __syncthreads();
    for (int s = 512; s >= 64; s >>= 1) {
        if (t < s) red[t] += red[t + s];
        __syncthreads();
    }
    if (t < 64)
        qkv[(size_t)mat * LVL * DD + (size_t)l * DD + ec * 64 + t] =
            red[t] + bias[(size_t)l * DD + ec * 64 + t];
}

// ---------------- K3: fused attention softmax + ctx + W1 matvec slice (ReLU) -------
// R10 structure: 32 blocks, each computes a 64-col h slice (W1 reads non-redundant).
__global__ __launch_bounds__(1024) void attn_h_kernel(const float* __restrict__ qkv,
                                                      const float* __restrict__ W1,
                                                      const float* __restrict__ b1,
                                                      float* __restrict__ h) {
    int l = blockIdx.x >> 3, ec = blockIdx.x & 7;
    int t = threadIdx.x;
    const float* q = qkv;
    const float* k = qkv + LVL * DD;
    const float* v = qkv + 2 * LVL * DD;

    __shared__ float red[1024];
    __shared__ float atw[LVL];
    __shared__ float ctx[DD];

    // scores: 4 dots of 512
    {
        int j = t >> 8, dd = t & 255;
        float a = q[l * DD + dd] * k[j * DD + dd]
                + q[l * DD + dd + 256] * k[j * DD + dd + 256];
        red[t] = a;
        __syncthreads();
        for (int s = 128; s >= 1; s >>= 1) {
            if ((t & 255) < s) red[t] += red[t + s];
            __syncthreads();
        }
        if (t == 0) {
            float sc[LVL], m = -1e30f;
            for (int jj = 0; jj < LVL; ++jj) {
                sc[jj] = (jj == l) ? -1e30f : red[jj * 256] * ATTN_SCALE;
                m = fmaxf(m, sc[jj]);
            }
            float ssum = 0.f;
            for (int jj = 0; jj < LVL; ++jj) { sc[jj] = expf(sc[jj] - m); ssum += sc[jj]; }
            float inv = 1.0f / ssum;
            for (int jj = 0; jj < LVL; ++jj) atw[jj] = sc[jj] * inv;
        }
        __syncthreads();
    }

    if (t < DD) {
        float c = 0.f;
        for (int jj = 0; jj < LVL; ++jj) c += atw[jj] * v[jj * DD + t];
        ctx[t] = c;
    }
    __syncthreads();

    int e = t & 63, dg = t >> 6;
    int ecol = ec * 64 + e;
    const float* Wl = W1 + (size_t)l * DD * DD;
    float acc = 0.f;
    for (int d = dg * 32; d < dg * 32 + 32; ++d)
        acc += ctx[d] * Wl[(size_t)d * DD + ecol];
    red[t] = acc;
    __syncthreads();
    for (int s = 512; s >= 64; s >>= 1) {
        if (t < s) red[t] += red[t + s];
        __syncthreads();
    }
    if (t < 64) {
        float r = red[t] + b1[(size_t)l * DD + ec * 64 + t];
        h[(size_t)l * DD + ec * 64 + t] = fmaxf(r, 0.f);
    }
}

// ---------------- K4: upd matvec ----------------
__global__ __launch_bounds__(1024) void matvec1024_kernel(const float* __restrict__ in,
                                                          const float* __restrict__ W,
                                                          const float* __restrict__ bias,
                                                          float* __restrict__ out) {
    int l = blockIdx.x >> 3, ec = blockIdx.x & 7;
    int t = threadIdx.x;
    __shared__ float red[1024];
    int e = t & 63, dg = t >> 6;
    int ecol = ec * 64 + e;
    const float* iv = in + (size_t)l * DD;
    const float* Wl = W + (size_t)l * DD * DD;
    float acc = 0.f;
    for (int d = dg * 32; d < dg * 32 + 32; ++d)
        acc += iv[d] * Wl[(size_t)d * DD + ecol];
    red[t] = acc;
    __syncthreads();
    for (int s = 512; s >= 64; s >>= 1) {
        if (t < s) red[t] += red[t + s];
        __syncthreads();
    }
    if (t < 64)
        out[(size_t)l * DD + ec * 64 + t] = red[t] + bias[(size_t)l * DD + ec * 64 + t];
}

// ---------------- K5: residual + LayerNorm (2-row, software-pipelined) -------------
// Descending; NT stores (A/B-proven R8/R9). NEW vs R10: next row-pair's 4 x-loads
// are issued at the TOP of each iteration, before the current pair's reduce/store
// chain, so HBM latency hides under the ~24-op shuffle chain. 16 uniform
// iterations per wave (262144 rows / 8192 waves / 2 rows). VGPR budget kept
// under the 64 cliff (R11's 4-row crossed it: 326 us).
__global__ __launch_bounds__(256) void final_ln_kernel(const float* __restrict__ x,
                                                       const float* __restrict__ upd,
                                                       const float* __restrict__ gamma,
                                                       const float* __restrict__ beta,
                                                       float* __restrict__ out) {
    int lane = threadIdx.x & 63;
    int wid = (blockIdx.x * blockDim.x + threadIdx.x) >> 6;
    const int NW = (2048 * 256) >> 6;          // 8192 waves
    const int totalRows = LVL * NN;            // 262144
    const int STEP = NW * 2;                   // rows consumed per grid sweep
    const int ITERS = totalRows / STEP;        // 16, uniform across waves

    int lprev = -1;
    float4 u0, u1, g0, g1, p0, p1;

    int r0 = totalRows - 2 - wid * 2;          // even; pair (r0, r0+1) same level
    const float4* xr = (const float4*)(x + (size_t)r0 * DD);
    float4 a0 = xr[lane];
    float4 c0 = xr[64 + lane];
    float4 a1 = xr[128 + lane];
    float4 c1 = xr[192 + lane];

    for (int j = 0; j < ITERS; ++j) {
        // ---- prefetch next iteration's row pair (hidden under this iter's chain)
        int r0n = r0 - STEP;
        float4 na0, nc0, na1, nc1;
        if (j < ITERS - 1) {
            const float4* xn = (const float4*)(x + (size_t)r0n * DD);
            na0 = xn[lane];
            nc0 = xn[64 + lane];
            na1 = xn[128 + lane];
            nc1 = xn[192 + lane];
        }

        int l = r0 >> 16;                      // NN = 65536
        if (l != lprev) {
            lprev = l;
            const float4* ur = (const float4*)(upd + (size_t)l * DD);
            u0 = ur[lane]; u1 = ur[64 + lane];
            const float4* gr = (const float4*)(gamma + (size_t)l * DD);
            g0 = gr[lane]; g1 = gr[64 + lane];
            const float4* br = (const float4*)(beta + (size_t)l * DD);
            p0 = br[lane]; p1 = br[64 + lane];
        }

        acc4(a0, u0); acc4(c0, u1);
        acc4(a1, u0); acc4(c1, u1);
        float s0  = a0.x + a0.y + a0.z + a0.w + c0.x + c0.y + c0.z + c0.w;
        float sq0 = a0.x*a0.x + a0.y*a0.y + a0.z*a0.z + a0.w*a0.w
                  + c0.x*c0.x + c0.y*c0.y + c0.z*c0.z + c0.w*c0.w;
        float s1  = a1.x + a1.y + a1.z + a1.w + c1.x + c1.y + c1.z + c1.w;
        float sq1 = a1.x*a1.x + a1.y*a1.y + a1.z*a1.z + a1.w*a1.w
                  + c1.x*c1.x + c1.y*c1.y + c1.z*c1.z + c1.w*c1.w;
        for (int off = 32; off >= 1; off >>= 1) {
            s0  += __shfl_down(s0, off);
            sq0 += __shfl_down(sq0, off);
            s1  += __shfl_down(s1, off);
            sq1 += __shfl_down(sq1, off);
        }
        s0 = __shfl(s0, 0);  sq0 = __shfl(sq0, 0);
        s1 = __shfl(s1, 0);  sq1 = __shfl(sq1, 0);
        float mu0 = s0 * (1.0f / DD);
        float var0 = sq0 * (1.0f / DD) - mu0 * mu0;
        float inv0 = rsqrtf(var0 + LN_EPS);
        float mu1 = s1 * (1.0f / DD);
        float var1 = sq1 * (1.0f / DD) - mu1 * mu1;
        float inv1 = rsqrtf(var1 + LN_EPS);
        float4 o;
        float* orow0 = out + (size_t)r0 * DD;
        float* orow1 = out + (size_t)(r0 + 1) * DD;
        o.x = (a0.x - mu0) * inv0 * g0.x + p0.x;
        o.y = (a0.y - mu0) * inv0 * g0.y + p0.y;
        o.z = (a0.z - mu0) * inv0 * g0.z + p0.z;
        o.w = (a0.w - mu0) * inv0 * g0.w + p0.w;
        __builtin_nontemporal_store(*(const f32x4*)&o, (f32x4*)(orow0) + lane);
        o.x = (c0.x - mu0) * inv0 * g1.x + p1.x;
        o.y = (c0.y - mu0) * inv0 * g1.y + p1.y;
        o.z = (c0.z - mu0) * inv0 * g1.z + p1.z;
        o.w = (c0.w - mu0) * inv0 * g1.w + p1.w;
        __builtin_nontemporal_store(*(const f32x4*)&o, (f32x4*)(orow0) + 64 + lane);
        o.x = (a1.x - mu1) * inv1 * g0.x + p0.x;
        o.y = (a1.y - mu1) * inv1 * g0.y + p0.y;
        o.z = (a1.z - mu1) * inv1 * g0.z + p0.z;
        o.w = (a1.w - mu1) * inv1 * g0.w + p0.w;
        __builtin_nontemporal_store(*(const f32x4*)&o, (f32x4*)(orow1) + lane);
        o.x = (c1.x - mu1) * inv1 * g1.x + p1.x;
        o.y = (c1.y - mu1) * inv1 * g1.y + p1.y;
        o.z = (c1.z - mu1) * inv1 * g1.z + p1.z;
        o.w = (c1.w - mu1) * inv1 * g1.w + p1.w;
        __builtin_nontemporal_store(*(const f32x4*)&o, (f32x4*)(orow1) + 64 + lane);

        // ---- rotate pipeline
        a0 = na0; c0 = nc0; a1 = na1; c1 = nc1;
        r0 = r0n;
    }
}

extern "C" void kernel_launch(void* const* d_in, const int* in_sizes, int n_in,
                              void* d_out, int out_size, void* d_ws, size_t ws_size,
                              hipStream_t stream) {
    const float* x     = (const float*)d_in[0];
    const float* Wq    = (const float*)d_in[1];
    const float* bq    = (const float*)d_in[2];
    const float* Wk    = (const float*)d_in[3];
    const float* bk    = (const float*)d_in[4];
    const float* Wv    = (const float*)d_in[5];
    const float* bv    = (const float*)d_in[6];
    const float* W1    = (const float*)d_in[7];
    const float* b1    = (const float*)d_in[8];
    const float* W2    = (const float*)d_in[9];
    const float* b2    = (const float*)d_in[10];
    const float* gamma = (const float*)d_in[11];
    const float* beta  = (const float*)d_in[12];
    float* out = (float*)d_out;
    float* ws = (float*)d_ws;

    float* partials = ws + WS_PARTIALS;
    float* qkv      = ws + WS_QKV;
    float* h        = ws + WS_H;
    float* upd      = ws + WS_UPD;

    colsum_kernel<<<LVL * NBLK, 256, 0, stream>>>(x, partials);
    qkv_kernel<<<112, 1024, 0, stream>>>(partials, Wq, bq, Wk, bk, Wv, bv, W1, W2, qkv);
    attn_h_kernel<<<32, 1024, 0, stream>>>(qkv, W1, b1, h);
    matvec1024_kernel<<<32, 1024, 0, stream>>>(h, W2, b2, upd);
    final_ln_kernel<<<2048, 256, 0, stream>>>(x, upd, gamma, beta, out);
}